// Round 13
// baseline (228.286 us; speedup 1.0000x reference)
//
#include <hip/hip_runtime.h>

#define D 64
#define NNODES 545
#define SNAPN 544   // max t+c
#define CN  64      // n-chunk rows staged in LDS (mono k_gate fallback)
#define CNP 32      // n-chunk granularity for slice boundaries (k_part)
#define NSL 4       // n-slices (k_part grid.y)
#define NMS 8       // merge slices

// ---------------- init: copy x -> H (d_out), transpose weights into ws ----------------
// wT layout (12 mats of 64x64, [e][d]): 0 taL,1 taR,2 caL,3 caR,4 tbL,5 tbR,6 cbL,7 cbR,8 uL,9 uR,10 oL,11 oR
__global__ void k_init(const float* __restrict__ x,
                       const float* __restrict__ w_ta, const float* __restrict__ w_ca,
                       const float* __restrict__ w_tb, const float* __restrict__ w_cb,
                       const float* __restrict__ w_u,  const float* __restrict__ w_o,
                       float* __restrict__ H, float* __restrict__ wT)
{
    int idx = blockIdx.x * 256 + threadIdx.x;
    const int NH = 2 * NNODES * D;  // 69760
    if (idx < NH) { H[idx] = x[idx]; return; }
    int j = idx - NH;
    if (j >= 12 * 4096) return;
    int mat = j >> 12;
    int r   = j & 4095;
    int e   = r >> 6;
    int dd  = r & 63;
    const float* src;
    switch (mat >> 1) {
        case 0: src = w_ta; break;
        case 1: src = w_ca; break;
        case 2: src = w_tb; break;
        case 3: src = w_cb; break;
        case 4: src = w_u;  break;
        default: src = w_o; break;
    }
    int half = mat & 1;
    wT[j] = src[dd * 128 + half * 64 + e];
}

// ---------------- kernel A: per-segment staging (verified r1/4/7/9/10/11/12) ----------
__global__ void k_stage(const float* __restrict__ H,
                        const float* __restrict__ wT,
                        float* __restrict__ snap,   // [2][544][64]
                        float* __restrict__ Pb,     // [2][544][64]
                        float* __restrict__ stT,    // [2][3][128][64]
                        float* __restrict__ stC,    // [2][3][128][64]
                        int off, int t, int c)
{
    __shared__ float Hs[4][64];
    __shared__ float PaS[4][64];
    int b = blockIdx.y;
    int tilesT = (t + 3) >> 2;
    int tile = blockIdx.x;
    int ln = threadIdx.x >> 6;
    int d  = threadIdx.x & 63;
    int regionC = (tile >= tilesT) ? 1 : 0;
    int tl = regionC ? (tile - tilesT) : tile;
    int n0 = tl * 4;
    int cnt = regionC ? c : t;
    int nodeBase = off + (regionC ? t : 0);
    int valid = (n0 + ln) < cnt;
    const float* Hb = H + b * NNODES * D;

    Hs[ln][d] = valid ? Hb[(nodeBase + n0 + ln) * D + d] : 0.0f;
    __syncthreads();

    const float* wA = wT + (regionC ? 2 * 4096 : 0);        // caL : taL
    const float* wB = wT + (regionC ? 6 * 4096 : 4 * 4096); // cbL : tbL
    float acc_a = 0.0f, acc_b = 0.0f;
#pragma unroll 8
    for (int e = 0; e < 64; e++) {
        float h = Hs[ln][e];
        acc_a = fmaf(wA[e * 64 + d], h, acc_a);
        acc_b = fmaf(wB[e * 64 + d], h, acc_b);
    }
    int gn = (regionC ? t : 0) + n0 + ln;
    float* snapB = snap + b * SNAPN * D;
    float* PbB   = Pb   + b * SNAPN * D;
    if (valid) {
        PbB[gn * D + d]   = acc_b;
        snapB[gn * D + d] = Hs[ln][d];
    }
    PaS[ln][d] = valid ? acc_a : -3.0e38f;
    __syncthreads();

    if (threadIdx.x < 64) {
        int dd = threadIdx.x;
        float mx = -3.0e38f;
#pragma unroll
        for (int l = 0; l < 4; l++) mx = fmaxf(mx, PaS[l][dd]);
        int lim = cnt - n0; if (lim > 4) lim = 4;
        float se = 0.0f, sw = 0.0f;
        for (int l = 0; l < lim; l++) {
            float ev = expf(PaS[l][dd] - mx);
            se += ev;
            sw += ev * Hs[l][dd];
        }
        float* st = (regionC ? stC : stT) + b * 3 * 128 * 64;
        st[0 * 8192 + tl * 64 + dd] = mx;
        st[1 * 8192 + tl * 64 + dd] = se;
        st[2 * 8192 + tl * 64 + dd] = sw;
    }
}

// ---------------- k_merge: single-level merge (fallback path only; verified r7/9) -----
__global__ void k_merge(const float* __restrict__ stT,
                        const float* __restrict__ stC,
                        float* __restrict__ stFin,
                        int t, int c)
{
    int r = blockIdx.x;
    int b = blockIdx.y;
    int d = threadIdx.x;
    const float* st = (r ? stC : stT) + b * 3 * 8192;
    int cnt = r ? c : t;
    int ntl = (cnt + 3) >> 2;
    float m = -3.0e38f, se = 0.0f, sw = 0.0f;
    for (int tl = 0; tl < ntl; tl++) {
        float m1 = st[tl * 64 + d];
        float s1 = st[8192 + tl * 64 + d];
        float w1 = st[2 * 8192 + tl * 64 + d];
        float nm = fmaxf(m, m1);
        float f0 = expf(m - nm), f1 = expf(m1 - nm);
        se = se * f0 + s1 * f1;
        sw = sw * f0 + w1 * f1;
        m  = nm;
    }
    float* o = stFin + (b * 2 + r) * 192;
    o[d] = m; o[64 + d] = se; o[128 + d] = sw;
}

// ---------------- k_part: B-part partials, DIRECT coalesced reads (no LDS) ------------
// grid: (kblk + 4, NSL, 2). Blocks with blockIdx.x >= kblk run the k_mergeA body
// (verbatim r11/12) for region r = e>>1, slice s = (e&1)*4 + blockIdx.y.
__global__ void k_part(const float* __restrict__ wT,
                       const float* __restrict__ snap,
                       const float* __restrict__ Pb,
                       const float* __restrict__ b_tb, const float* __restrict__ b_cb,
                       const float* __restrict__ stT, const float* __restrict__ stC,
                       float* __restrict__ stMid,  // [(b*2+r)*NMS+s][3][64]
                       float* __restrict__ accW,   // [NSL][2][512][64]
                       int off, int t, int c)
{
    int kblk = gridDim.x - 4;
    int b  = blockIdx.z;

    if (blockIdx.x >= kblk) {
        // ---- mergeA rider (r11/12 body, verbatim) ----
        if (threadIdx.x < 64) {
            int e = blockIdx.x - kblk;        // 0..3
            int r = e >> 1;                   // region
            int s = (e & 1) * 4 + blockIdx.y; // slice 0..7
            int d = threadIdx.x;
            const float* st = (r ? stC : stT) + b * 3 * 8192;
            int cnt = r ? c : t;
            int ntl = (cnt + 3) >> 2;
            int tl0 = s * 16, tl1 = tl0 + 16; if (tl1 > ntl) tl1 = ntl;
            float m = -3.0e38f, se = 0.0f, sw = 0.0f;
            for (int tl = tl0; tl < tl1; tl++) {
                float m1 = st[tl * 64 + d];
                float s1 = st[8192 + tl * 64 + d];
                float w1 = st[2 * 8192 + tl * 64 + d];
                float nm = fmaxf(m, m1);
                float f0 = expf(m - nm), f1 = expf(m1 - nm);
                se = se * f0 + s1 * f1;
                sw = sw * f0 + w1 * f1;
                m  = nm;
            }
            float* o = stMid + ((b * 2 + r) * NMS + s) * 192;
            o[d] = m; o[64 + d] = se; o[128 + d] = sw;
        }
        return;
    }

    int s  = blockIdx.y;
    int kl = threadIdx.x >> 6;
    int d  = threadIdx.x & 63;
    int k  = blockIdx.x * 4 + kl;
    int valid = (k < c) ? 1 : 0;
    int kk = valid ? k : 0;
    const float* snapB = snap + b * SNAPN * D;
    const float* PbB   = Pb   + b * SNAPN * D;

    // ---- b-gate Q offsets (verified pattern) ----
    float offTb = b_tb[d], offCb = b_cb[d];
    const float* tbR = wT + 5 * 4096;
    const float* cbR = wT + 7 * 4096;
    const float* cptr = snapB + (t + kk) * 64;
#pragma unroll 8
    for (int e = 0; e < 64; e++) {
        float cv = cptr[e];
        offTb = fmaf(tbR[e * 64 + d], cv, offTb);
        offCb = fmaf(cbR[e * 64 + d], cv, offCb);
    }

    // ---- B-part over this slice's row range (same boundaries as r12 chunk slicing) ----
    int NTOT = t + c;
    int nch = (NTOT + CNP - 1) / CNP;
    int cps = (nch + NSL - 1) / NSL;
    int nlo = s * cps * CNP;
    int nhi = (s + 1) * cps * CNP; if (nhi > NTOT) nhi = NTOT;
    float acc = 0.0f;
#pragma unroll 8
    for (int n = nlo; n < nhi; n++) {
        float pb = PbB[n * 64 + d];        // wave-coalesced 256B line
        float sv = snapB[n * 64 + d];
        float p = pb + ((n < t) ? offTb : offCb);
        float f = p / (1.0f + fabsf(p));
        acc = fmaf(f, sv, acc);
    }
    accW[((s * 2 + b) * 512 + k) * 64 + d] = acc;
}

// ---------------- k_fin: combine + epilogue (verified r12; mergeB inlined) ------------
__global__ void k_fin(float* __restrict__ H,
                      const float* __restrict__ wT,
                      const float* __restrict__ snap,
                      const float* __restrict__ stMid,
                      const float* __restrict__ b_ta, const float* __restrict__ b_ca,
                      const float* __restrict__ w_mix,
                      const float* __restrict__ b_u, const float* __restrict__ b_o,
                      const float* __restrict__ accW,
                      float* __restrict__ updWS,
                      int off, int t, int c, int storeUpd, int reapply, int prev_i)
{
    __shared__ float mS[4][64];
    __shared__ float sS[4][64];
    int b  = blockIdx.y;
    int kl = threadIdx.x >> 6;
    int d  = threadIdx.x & 63;
    int k  = blockIdx.x * 4 + kl;
    int valid = (k < c) ? 1 : 0;
    int i = off + t;
    const float* snapB = snap + b * SNAPN * D;

    // ---- mergeB inlined (verbatim r12) ----
    float mT = -3.0e38f, seT = 0.0f, swT = 0.0f;
    {
        const float* base = stMid + (b * 2 + 0) * NMS * 192;
#pragma unroll
        for (int s = 0; s < NMS; s++) {
            const float* p = base + s * 192;
            float m1 = p[d], s1 = p[64 + d], w1 = p[128 + d];
            float nm = fmaxf(mT, m1);
            float f0 = expf(mT - nm), f1 = expf(m1 - nm);
            seT = seT * f0 + s1 * f1;
            swT = swT * f0 + w1 * f1;
            mT = nm;
        }
    }
    float mC = -3.0e38f, seC = 0.0f, swC = 0.0f;
    {
        const float* base = stMid + (b * 2 + 1) * NMS * 192;
#pragma unroll
        for (int s = 0; s < NMS; s++) {
            const float* p = base + s * 192;
            float m1 = p[d], s1 = p[64 + d], w1 = p[128 + d];
            float nm = fmaxf(mC, m1);
            float f0 = expf(mC - nm), f1 = expf(m1 - nm);
            seC = seC * f0 + s1 * f1;
            swC = swC * f0 + w1 * f1;
            mC = nm;
        }
    }

    // ---- a-gate Q offsets (verified) ----
    float offTa = b_ta[d], offCa = b_ca[d];
    const float* taR = wT + 1 * 4096;
    const float* caR = wT + 3 * 4096;
    int kk = valid ? k : 0;
    const float* cptr = snapB + (t + kk) * 64;
#pragma unroll 8
    for (int e = 0; e < 64; e++) {
        float cv = cptr[e];
        offTa = fmaf(taR[e * 64 + d], cv, offTa);
        offCa = fmaf(caR[e * 64 + d], cv, offCa);
    }

    // ---- A part ----
    float aT = mT + offTa, aC = mC + offCa;
    float M  = fmaxf(aT, aC);
    float eT = expf(aT - M), eC = expf(aC - M);
    float denom = eT * seT + eC * seC;
    float Apart = w_mix[d] * (eT * swT + eC * swC) / denom;

    // ---- B part = sum of slice partials ----
    float acc = 0.0f;
#pragma unroll
    for (int s = 0; s < NSL; s++) acc += accW[((s * 2 + b) * 512 + k) * 64 + d];
    float mval = Apart + acc;

    mS[kl][d] = mval;
    sS[kl][d] = snapB[(t + kk) * 64 + d];
    __syncthreads();

    // ---- u, o, update (verified) ----
    const float* uL = wT + 8 * 4096;
    const float* uR = wT + 9 * 4096;
    const float* oL = wT + 10 * 4096;
    const float* oR = wT + 11 * 4096;
    float zU = b_u[d], zO = b_o[d];
#pragma unroll 8
    for (int e = 0; e < 64; e++) {
        float mv = mS[kl][e], sv = sS[kl][e];
        zU = fmaf(mv, uL[e * 64 + d], zU);
        zU = fmaf(sv, uR[e * 64 + d], zU);
        zO = fmaf(mv, oL[e * 64 + d], zO);
        zO = fmaf(sv, oR[e * 64 + d], zO);
    }
    float u  = 1.0f / (1.0f + expf(-zU));
    float o  = fmaxf(zO, 0.0f);
    float mm = mS[kl][d];
    float sv = sS[kl][d];
    float upd = u * o + (1.0f - u) * mm - sv;

    float* Hb = H + b * NNODES * D;
    if (valid) {
        Hb[(i + k) * D + d] += upd;
        if (storeUpd) updWS[b * 2048 + k * 64 + d] = upd;
    }
    if (reapply && blockIdx.x == 0) {
#pragma unroll
        for (int r = 0; r < 8; r++) {
            int idx = threadIdx.x + 256 * r;  // 2048 = 32 nodes * 64
            Hb[(prev_i + (idx >> 6)) * D + (idx & 63)] += updWS[b * 2048 + idx];
        }
    }
}

// ---------------- fallback: r9 mono k_gate, byte-identical ----------------
__global__ void k_gate(float* __restrict__ H,
                       const float* __restrict__ wT,
                       const float* __restrict__ snap,
                       const float* __restrict__ Pb,
                       const float* __restrict__ stFin,
                       const float* __restrict__ b_ta, const float* __restrict__ b_ca,
                       const float* __restrict__ b_tb, const float* __restrict__ b_cb,
                       const float* __restrict__ w_mix,
                       const float* __restrict__ b_u, const float* __restrict__ b_o,
                       float* __restrict__ updWS,
                       int off, int t, int c, int storeUpd, int reapply, int prev_i)
{
    __shared__ float PS[CN][D];
    __shared__ float SS[CN][D];
    __shared__ float mS[4][64];
    __shared__ float sS[4][64];
    int b  = blockIdx.y;
    int kl = threadIdx.x >> 6;
    int d  = threadIdx.x & 63;
    int k  = blockIdx.x * 4 + kl;
    int valid = (k < c) ? 1 : 0;
    int i = off + t;
    const float* snapB = snap + b * SNAPN * D;
    const float* PbB   = Pb   + b * SNAPN * D;

    const float* fB = stFin + b * 384;
    float mT = fB[d],       seT = fB[64 + d],  swT = fB[128 + d];
    float mC = fB[192 + d], seC = fB[256 + d], swC = fB[320 + d];

    float offTa = b_ta[d], offCa = b_ca[d], offTb = b_tb[d], offCb = b_cb[d];
    const float* taR = wT + 1 * 4096;
    const float* caR = wT + 3 * 4096;
    const float* tbR = wT + 5 * 4096;
    const float* cbR = wT + 7 * 4096;
    int kk = valid ? k : 0;
    const float* cptr = snapB + (t + kk) * 64;
#pragma unroll 8
    for (int e = 0; e < 64; e++) {
        float cv = cptr[e];
        offTa = fmaf(taR[e * 64 + d], cv, offTa);
        offCa = fmaf(caR[e * 64 + d], cv, offCa);
        offTb = fmaf(tbR[e * 64 + d], cv, offTb);
        offCb = fmaf(cbR[e * 64 + d], cv, offCb);
    }

    float aT = mT + offTa, aC = mC + offCa;
    float M  = fmaxf(aT, aC);
    float eT = expf(aT - M), eC = expf(aC - M);
    float denom = eT * seT + eC * seC;
    float Apart = w_mix[d] * (eT * swT + eC * swC) / denom;

    float acc = 0.0f;
    int NTOT = t + c;
    for (int n0 = 0; n0 < NTOT; n0 += CN) {
        int cnt = NTOT - n0; if (cnt > CN) cnt = CN;
        __syncthreads();
        int tot4 = cnt * (D / 4);
        const float4* gp = (const float4*)(PbB   + n0 * D);
        const float4* gs = (const float4*)(snapB + n0 * D);
        float4* lp = (float4*)&PS[0][0];
        float4* ls = (float4*)&SS[0][0];
        for (int idx4 = threadIdx.x; idx4 < tot4; idx4 += 256) {
            lp[idx4] = gp[idx4];
            ls[idx4] = gs[idx4];
        }
        __syncthreads();
#pragma unroll 8
        for (int n = 0; n < cnt; n++) {
            int gn = n0 + n;
            float p = PS[n][d] + ((gn < t) ? offTb : offCb);
            float f = p / (1.0f + fabsf(p));
            acc = fmaf(f, SS[n][d], acc);
        }
    }
    float mval = Apart + acc;

    mS[kl][d] = mval;
    sS[kl][d] = snapB[(t + kk) * 64 + d];
    __syncthreads();

    const float* uL = wT + 8 * 4096;
    const float* uR = wT + 9 * 4096;
    const float* oL = wT + 10 * 4096;
    const float* oR = wT + 11 * 4096;
    float zU = b_u[d], zO = b_o[d];
#pragma unroll 8
    for (int e = 0; e < 64; e++) {
        float mv = mS[kl][e], sv = sS[kl][e];
        zU = fmaf(mv, uL[e * 64 + d], zU);
        zU = fmaf(sv, uR[e * 64 + d], zU);
        zO = fmaf(mv, oL[e * 64 + d], zO);
        zO = fmaf(sv, oR[e * 64 + d], zO);
    }
    float u  = 1.0f / (1.0f + expf(-zU));
    float o  = fmaxf(zO, 0.0f);
    float mm = mS[kl][d];
    float sv = sS[kl][d];
    float upd = u * o + (1.0f - u) * mm - sv;

    float* Hb = H + b * NNODES * D;
    if (valid) {
        Hb[(i + k) * D + d] += upd;
        if (storeUpd) updWS[b * 2048 + k * 64 + d] = upd;
    }
    if (reapply && blockIdx.x == 0) {
#pragma unroll
        for (int r = 0; r < 8; r++) {
            int idx = threadIdx.x + 256 * r;
            Hb[(prev_i + (idx >> 6)) * D + (idx & 63)] += updWS[b * 2048 + idx];
        }
    }
}

extern "C" void kernel_launch(void* const* d_in, const int* in_sizes, int n_in,
                              void* d_out, int out_size, void* d_ws, size_t ws_size,
                              hipStream_t stream) {
    const float* x    = (const float*)d_in[0];
    const float* w_ta = (const float*)d_in[2];
    const float* b_ta = (const float*)d_in[3];
    const float* w_ca = (const float*)d_in[4];
    const float* b_ca = (const float*)d_in[5];
    const float* w_tb = (const float*)d_in[6];
    const float* b_tb = (const float*)d_in[7];
    const float* w_cb = (const float*)d_in[8];
    const float* b_cb = (const float*)d_in[9];
    const float* w_mix= (const float*)d_in[10];
    const float* w_u  = (const float*)d_in[11];
    const float* b_u  = (const float*)d_in[12];
    const float* w_o  = (const float*)d_in[13];
    const float* b_o  = (const float*)d_in[14];

    float* H  = (float*)d_out;           // evolving state, [2][545][64]
    float* ws = (float*)d_ws;
    float* wT    = ws;                   // 12*4096 = 49152
    float* snap  = wT + 49152;           // 69632
    float* Pb    = snap + 69632;         // 69632
    float* stT   = Pb + 69632;           // 49152
    float* stC   = stT + 49152;          // 49152
    float* upd   = stC + 49152;          // 4096
    float* stFin = upd + 4096;           // 768
    float* accW  = stFin + 768;          // NSL*2*512*64 = 262144
    float* stMid = accW + 262144;        // 2*2*NMS*3*64 = 6144

    const size_t NEEDED = (size_t)(49152 + 69632 + 69632 + 49152 + 49152 + 4096 + 768
                                   + (size_t)NSL * 2 * 512 * 64 + 2 * 2 * NMS * 192) * 4;
    int useSplit = (ws_size >= NEEDED) ? 1 : 0;

    {
        int total = 2 * NNODES * D + 12 * 4096;
        k_init<<<dim3((total + 255) / 256), 256, 0, stream>>>(
            x, w_ta, w_ca, w_tb, w_cb, w_u, w_o, H, wT);
    }

    struct St { int off, t, c, store, reapply, prev_i; };
    const St steps[4] = {
        {0,   1,  32, 1, 0, 0},
        {1,  32, 512, 0, 1, 1},
        {0, 512,  32, 1, 0, 0},
        {512, 32,  1, 0, 1, 512},
    };
    for (int p = 0; p < 2; p++) {
        for (int s = 0; s < 4; s++) {
            St st = steps[s];
            int tilesT = (st.t + 3) / 4, tilesC = (st.c + 3) / 4;
            k_stage<<<dim3(tilesT + tilesC, 2), 256, 0, stream>>>(
                H, wT, snap, Pb, stT, stC, st.off, st.t, st.c);
            int kblk = (st.c + 3) / 4;
            if (useSplit) {
                k_part<<<dim3(kblk + 4, NSL, 2), 256, 0, stream>>>(
                    wT, snap, Pb, b_tb, b_cb, stT, stC, stMid, accW,
                    st.off, st.t, st.c);
                k_fin<<<dim3(kblk, 2), 256, 0, stream>>>(
                    H, wT, snap, stMid, b_ta, b_ca, w_mix, b_u, b_o, accW, upd,
                    st.off, st.t, st.c, st.store, st.reapply, st.prev_i);
            } else {
                k_merge<<<dim3(2, 2), 64, 0, stream>>>(
                    stT, stC, stFin, st.t, st.c);
                k_gate<<<dim3(kblk, 2), 256, 0, stream>>>(
                    H, wT, snap, Pb, stFin,
                    b_ta, b_ca, b_tb, b_cb, w_mix, b_u, b_o, upd,
                    st.off, st.t, st.c, st.store, st.reapply, st.prev_i);
            }
        }
    }
}

// Round 14
// 225.852 us; speedup vs baseline: 1.0108x; 1.0108x over previous
//
#include <hip/hip_runtime.h>

#define D 64
#define NNODES 545
#define SNAPN 544   // max t+c
#define CN  64      // n-chunk rows staged in LDS (mono k_gate paths)
#define CNP 32      // n-chunk granularity for slice boundaries (k_part)
#define NSLMAX 16   // accW slice capacity
#define NMS 8       // merge slices

// ---------------- init: copy x -> H (d_out), transpose weights into ws ----------------
__global__ void k_init(const float* __restrict__ x,
                       const float* __restrict__ w_ta, const float* __restrict__ w_ca,
                       const float* __restrict__ w_tb, const float* __restrict__ w_cb,
                       const float* __restrict__ w_u,  const float* __restrict__ w_o,
                       float* __restrict__ H, float* __restrict__ wT)
{
    int idx = blockIdx.x * 256 + threadIdx.x;
    const int NH = 2 * NNODES * D;  // 69760
    if (idx < NH) { H[idx] = x[idx]; return; }
    int j = idx - NH;
    if (j >= 12 * 4096) return;
    int mat = j >> 12;
    int r   = j & 4095;
    int e   = r >> 6;
    int dd  = r & 63;
    const float* src;
    switch (mat >> 1) {
        case 0: src = w_ta; break;
        case 1: src = w_ca; break;
        case 2: src = w_tb; break;
        case 3: src = w_cb; break;
        case 4: src = w_u;  break;
        default: src = w_o; break;
    }
    int half = mat & 1;
    wT[j] = src[dd * 128 + half * 64 + e];
}

// ---------------- kernel A: per-segment staging (verified r1/4/7/9-13) ----------------
__global__ void k_stage(const float* __restrict__ H,
                        const float* __restrict__ wT,
                        float* __restrict__ snap,   // [2][544][64]
                        float* __restrict__ Pb,     // [2][544][64]
                        float* __restrict__ stT,    // [2][3][128][64]
                        float* __restrict__ stC,    // [2][3][128][64]
                        int off, int t, int c)
{
    __shared__ float Hs[4][64];
    __shared__ float PaS[4][64];
    int b = blockIdx.y;
    int tilesT = (t + 3) >> 2;
    int tile = blockIdx.x;
    int ln = threadIdx.x >> 6;
    int d  = threadIdx.x & 63;
    int regionC = (tile >= tilesT) ? 1 : 0;
    int tl = regionC ? (tile - tilesT) : tile;
    int n0 = tl * 4;
    int cnt = regionC ? c : t;
    int nodeBase = off + (regionC ? t : 0);
    int valid = (n0 + ln) < cnt;
    const float* Hb = H + b * NNODES * D;

    Hs[ln][d] = valid ? Hb[(nodeBase + n0 + ln) * D + d] : 0.0f;
    __syncthreads();

    const float* wA = wT + (regionC ? 2 * 4096 : 0);        // caL : taL
    const float* wB = wT + (regionC ? 6 * 4096 : 4 * 4096); // cbL : tbL
    float acc_a = 0.0f, acc_b = 0.0f;
#pragma unroll 8
    for (int e = 0; e < 64; e++) {
        float h = Hs[ln][e];
        acc_a = fmaf(wA[e * 64 + d], h, acc_a);
        acc_b = fmaf(wB[e * 64 + d], h, acc_b);
    }
    int gn = (regionC ? t : 0) + n0 + ln;
    float* snapB = snap + b * SNAPN * D;
    float* PbB   = Pb   + b * SNAPN * D;
    if (valid) {
        PbB[gn * D + d]   = acc_b;
        snapB[gn * D + d] = Hs[ln][d];
    }
    PaS[ln][d] = valid ? acc_a : -3.0e38f;
    __syncthreads();

    if (threadIdx.x < 64) {
        int dd = threadIdx.x;
        float mx = -3.0e38f;
#pragma unroll
        for (int l = 0; l < 4; l++) mx = fmaxf(mx, PaS[l][dd]);
        int lim = cnt - n0; if (lim > 4) lim = 4;
        float se = 0.0f, sw = 0.0f;
        for (int l = 0; l < lim; l++) {
            float ev = expf(PaS[l][dd] - mx);
            se += ev;
            sw += ev * Hs[l][dd];
        }
        float* st = (regionC ? stC : stT) + b * 3 * 128 * 64;
        st[0 * 8192 + tl * 64 + dd] = mx;
        st[1 * 8192 + tl * 64 + dd] = se;
        st[2 * 8192 + tl * 64 + dd] = sw;
    }
}

// ---------------- k_merge: single-level merge (fallback path only; verified r7/9) -----
__global__ void k_merge(const float* __restrict__ stT,
                        const float* __restrict__ stC,
                        float* __restrict__ stFin,
                        int t, int c)
{
    int r = blockIdx.x;
    int b = blockIdx.y;
    int d = threadIdx.x;
    const float* st = (r ? stC : stT) + b * 3 * 8192;
    int cnt = r ? c : t;
    int ntl = (cnt + 3) >> 2;
    float m = -3.0e38f, se = 0.0f, sw = 0.0f;
    for (int tl = 0; tl < ntl; tl++) {
        float m1 = st[tl * 64 + d];
        float s1 = st[8192 + tl * 64 + d];
        float w1 = st[2 * 8192 + tl * 64 + d];
        float nm = fmaxf(m, m1);
        float f0 = expf(m - nm), f1 = expf(m1 - nm);
        se = se * f0 + s1 * f1;
        sw = sw * f0 + w1 * f1;
        m  = nm;
    }
    float* o = stFin + (b * 2 + r) * 192;
    o[d] = m; o[64 + d] = se; o[128 + d] = sw;
}

// ---------------- k_gate4: round-4 VERIFIED mono gate (inline merge) for tiny steps ---
__global__ void k_gate4(float* __restrict__ H,
                        const float* __restrict__ wT,
                        const float* __restrict__ snap,
                        const float* __restrict__ Pb,
                        const float* __restrict__ stT,
                        const float* __restrict__ stC,
                        const float* __restrict__ b_ta, const float* __restrict__ b_ca,
                        const float* __restrict__ b_tb, const float* __restrict__ b_cb,
                        const float* __restrict__ w_mix,
                        const float* __restrict__ b_u, const float* __restrict__ b_o,
                        float* __restrict__ updWS,
                        int off, int t, int c, int storeUpd, int reapply, int prev_i)
{
    __shared__ float PS[CN][D];   // 16KB Pb chunk
    __shared__ float SS[CN][D];   // 16KB snap chunk
    __shared__ float mS[4][64];
    __shared__ float sS[4][64];
    int b  = blockIdx.y;
    int kl = threadIdx.x >> 6;
    int d  = threadIdx.x & 63;
    int k  = blockIdx.x * 4 + kl;
    int valid = (k < c) ? 1 : 0;
    int i = off + t;
    const float* snapB = snap + b * SNAPN * D;
    const float* PbB   = Pb   + b * SNAPN * D;

    // ---- sequential softmax-stat merge (r4 verbatim) ----
    int nT = (t + 3) >> 2, nC = (c + 3) >> 2;
    const float* sT = stT + b * 3 * 8192;
    float mT = -3.0e38f, seT = 0.0f, swT = 0.0f;
    for (int tl = 0; tl < nT; tl++) {
        float m1 = sT[tl * 64 + d];
        float s1 = sT[8192 + tl * 64 + d];
        float w1 = sT[2 * 8192 + tl * 64 + d];
        float nm = fmaxf(mT, m1);
        float f0 = expf(mT - nm), f1 = expf(m1 - nm);
        seT = seT * f0 + s1 * f1;
        swT = swT * f0 + w1 * f1;
        mT = nm;
    }
    const float* sC = stC + b * 3 * 8192;
    float mC = -3.0e38f, seC = 0.0f, swC = 0.0f;
    for (int tl = 0; tl < nC; tl++) {
        float m1 = sC[tl * 64 + d];
        float s1 = sC[8192 + tl * 64 + d];
        float w1 = sC[2 * 8192 + tl * 64 + d];
        float nm = fmaxf(mC, m1);
        float f0 = expf(mC - nm), f1 = expf(m1 - nm);
        seC = seC * f0 + s1 * f1;
        swC = swC * f0 + w1 * f1;
        mC = nm;
    }

    // ---- Q offsets (r4 verbatim) ----
    float offTa = b_ta[d], offCa = b_ca[d], offTb = b_tb[d], offCb = b_cb[d];
    const float* taR = wT + 1 * 4096;
    const float* caR = wT + 3 * 4096;
    const float* tbR = wT + 5 * 4096;
    const float* cbR = wT + 7 * 4096;
    int kk = valid ? k : 0;
    const float* cptr = snapB + (t + kk) * 64;
#pragma unroll 4
    for (int e = 0; e < 64; e++) {
        float cv = cptr[e];
        offTa = fmaf(taR[e * 64 + d], cv, offTa);
        offCa = fmaf(caR[e * 64 + d], cv, offCa);
        offTb = fmaf(tbR[e * 64 + d], cv, offTb);
        offCb = fmaf(cbR[e * 64 + d], cv, offCb);
    }

    // ---- A part (r4 verbatim) ----
    float aT = mT + offTa, aC = mC + offCa;
    float M  = fmaxf(aT, aC);
    float eT = expf(aT - M), eC = expf(aC - M);
    float denom = eT * seT + eC * seC;
    float Apart = w_mix[d] * (eT * swT + eC * swC) / denom;

    // ---- B part: LDS-chunked (r4 verbatim) ----
    float acc = 0.0f;
    int NTOT = t + c;
    for (int n0 = 0; n0 < NTOT; n0 += CN) {
        int cnt = NTOT - n0; if (cnt > CN) cnt = CN;
        __syncthreads();
        int tot4 = cnt * (D / 4);
        const float4* gp = (const float4*)(PbB   + n0 * D);
        const float4* gs = (const float4*)(snapB + n0 * D);
        float4* lp = (float4*)&PS[0][0];
        float4* ls = (float4*)&SS[0][0];
        for (int idx4 = threadIdx.x; idx4 < tot4; idx4 += 256) {
            lp[idx4] = gp[idx4];
            ls[idx4] = gs[idx4];
        }
        __syncthreads();
        for (int n = 0; n < cnt; n++) {
            int gn = n0 + n;
            float p = PS[n][d] + ((gn < t) ? offTb : offCb);
            float f = p / (1.0f + fabsf(p));
            acc = fmaf(f, SS[n][d], acc);
        }
    }
    float mval = Apart + acc;

    mS[kl][d] = mval;
    sS[kl][d] = snapB[(t + kk) * 64 + d];
    __syncthreads();

    // ---- u, o, update (r4 verbatim) ----
    const float* uL = wT + 8 * 4096;
    const float* uR = wT + 9 * 4096;
    const float* oL = wT + 10 * 4096;
    const float* oR = wT + 11 * 4096;
    float zU = b_u[d], zO = b_o[d];
#pragma unroll 4
    for (int e = 0; e < 64; e++) {
        float mv = mS[kl][e], sv = sS[kl][e];
        zU = fmaf(mv, uL[e * 64 + d], zU);
        zU = fmaf(sv, uR[e * 64 + d], zU);
        zO = fmaf(mv, oL[e * 64 + d], zO);
        zO = fmaf(sv, oR[e * 64 + d], zO);
    }
    float u  = 1.0f / (1.0f + expf(-zU));
    float o  = fmaxf(zO, 0.0f);
    float mm = mS[kl][d];
    float sv = sS[kl][d];
    float upd = u * o + (1.0f - u) * mm - sv;

    float* Hb = H + b * NNODES * D;
    if (valid) {
        Hb[(i + k) * D + d] += upd;
        if (storeUpd) updWS[b * 2048 + k * 64 + d] = upd;
    }
    if (reapply && blockIdx.x == 0) {
#pragma unroll
        for (int r = 0; r < 8; r++) {
            int idx = threadIdx.x + 256 * r;  // 2048 = 32 nodes * 64
            Hb[(prev_i + (idx >> 6)) * D + (idx & 63)] += updWS[b * 2048 + idx];
        }
    }
}

// ---------------- k_part: B-part partials, direct reads (r13) + mergeA riders ---------
__global__ void k_part(const float* __restrict__ wT,
                       const float* __restrict__ snap,
                       const float* __restrict__ Pb,
                       const float* __restrict__ b_tb, const float* __restrict__ b_cb,
                       const float* __restrict__ stT, const float* __restrict__ stC,
                       float* __restrict__ stMid,  // [(b*2+r)*NMS+s][3][64]
                       float* __restrict__ accW,   // [NSLMAX][2][512][64]
                       int off, int t, int c, int nsl)
{
    int kblk = gridDim.x - 4;
    int b  = blockIdx.z;

    if (blockIdx.x >= kblk) {
        // ---- mergeA rider (r11/12 body, verbatim; only y<4 lanes carry work) ----
        if (blockIdx.y < 4 && threadIdx.x < 64) {
            int e = blockIdx.x - kblk;        // 0..3
            int r = e >> 1;                   // region
            int s = (e & 1) * 4 + blockIdx.y; // slice 0..7
            int d = threadIdx.x;
            const float* st = (r ? stC : stT) + b * 3 * 8192;
            int cnt = r ? c : t;
            int ntl = (cnt + 3) >> 2;
            int tl0 = s * 16, tl1 = tl0 + 16; if (tl1 > ntl) tl1 = ntl;
            float m = -3.0e38f, se = 0.0f, sw = 0.0f;
            for (int tl = tl0; tl < tl1; tl++) {
                float m1 = st[tl * 64 + d];
                float s1 = st[8192 + tl * 64 + d];
                float w1 = st[2 * 8192 + tl * 64 + d];
                float nm = fmaxf(m, m1);
                float f0 = expf(m - nm), f1 = expf(m1 - nm);
                se = se * f0 + s1 * f1;
                sw = sw * f0 + w1 * f1;
                m  = nm;
            }
            float* o = stMid + ((b * 2 + r) * NMS + s) * 192;
            o[d] = m; o[64 + d] = se; o[128 + d] = sw;
        }
        return;
    }

    int s  = blockIdx.y;
    int kl = threadIdx.x >> 6;
    int d  = threadIdx.x & 63;
    int k  = blockIdx.x * 4 + kl;
    int valid = (k < c) ? 1 : 0;
    int kk = valid ? k : 0;
    const float* snapB = snap + b * SNAPN * D;
    const float* PbB   = Pb   + b * SNAPN * D;

    // ---- b-gate Q offsets (verified pattern) ----
    float offTb = b_tb[d], offCb = b_cb[d];
    const float* tbR = wT + 5 * 4096;
    const float* cbR = wT + 7 * 4096;
    const float* cptr = snapB + (t + kk) * 64;
#pragma unroll 8
    for (int e = 0; e < 64; e++) {
        float cv = cptr[e];
        offTb = fmaf(tbR[e * 64 + d], cv, offTb);
        offCb = fmaf(cbR[e * 64 + d], cv, offCb);
    }

    // ---- B-part over this slice's row range (chunk-derived boundaries) ----
    int NTOT = t + c;
    int nch = (NTOT + CNP - 1) / CNP;
    int cps = (nch + nsl - 1) / nsl;
    int nlo = s * cps * CNP;
    int nhi = (s + 1) * cps * CNP; if (nhi > NTOT) nhi = NTOT;
    float acc = 0.0f;
#pragma unroll 8
    for (int n = nlo; n < nhi; n++) {
        float pb = PbB[n * 64 + d];        // wave-coalesced 256B line
        float sv = snapB[n * 64 + d];
        float p = pb + ((n < t) ? offTb : offCb);
        float f = p / (1.0f + fabsf(p));
        acc = fmaf(f, sv, acc);
    }
    accW[((s * 2 + b) * 512 + k) * 64 + d] = acc;
}

// ---------------- k_fin: combine + epilogue (r12/13; runtime nsl) ---------------------
__global__ void k_fin(float* __restrict__ H,
                      const float* __restrict__ wT,
                      const float* __restrict__ snap,
                      const float* __restrict__ stMid,
                      const float* __restrict__ b_ta, const float* __restrict__ b_ca,
                      const float* __restrict__ w_mix,
                      const float* __restrict__ b_u, const float* __restrict__ b_o,
                      const float* __restrict__ accW,
                      float* __restrict__ updWS,
                      int off, int t, int c, int storeUpd, int reapply, int prev_i,
                      int nsl)
{
    __shared__ float mS[4][64];
    __shared__ float sS[4][64];
    int b  = blockIdx.y;
    int kl = threadIdx.x >> 6;
    int d  = threadIdx.x & 63;
    int k  = blockIdx.x * 4 + kl;
    int valid = (k < c) ? 1 : 0;
    int i = off + t;
    const float* snapB = snap + b * SNAPN * D;

    // ---- mergeB inlined (verbatim r12/13) ----
    float mT = -3.0e38f, seT = 0.0f, swT = 0.0f;
    {
        const float* base = stMid + (b * 2 + 0) * NMS * 192;
#pragma unroll
        for (int s = 0; s < NMS; s++) {
            const float* p = base + s * 192;
            float m1 = p[d], s1 = p[64 + d], w1 = p[128 + d];
            float nm = fmaxf(mT, m1);
            float f0 = expf(mT - nm), f1 = expf(m1 - nm);
            seT = seT * f0 + s1 * f1;
            swT = swT * f0 + w1 * f1;
            mT = nm;
        }
    }
    float mC = -3.0e38f, seC = 0.0f, swC = 0.0f;
    {
        const float* base = stMid + (b * 2 + 1) * NMS * 192;
#pragma unroll
        for (int s = 0; s < NMS; s++) {
            const float* p = base + s * 192;
            float m1 = p[d], s1 = p[64 + d], w1 = p[128 + d];
            float nm = fmaxf(mC, m1);
            float f0 = expf(mC - nm), f1 = expf(m1 - nm);
            seC = seC * f0 + s1 * f1;
            swC = swC * f0 + w1 * f1;
            mC = nm;
        }
    }

    // ---- a-gate Q offsets (verified) ----
    float offTa = b_ta[d], offCa = b_ca[d];
    const float* taR = wT + 1 * 4096;
    const float* caR = wT + 3 * 4096;
    int kk = valid ? k : 0;
    const float* cptr = snapB + (t + kk) * 64;
#pragma unroll 8
    for (int e = 0; e < 64; e++) {
        float cv = cptr[e];
        offTa = fmaf(taR[e * 64 + d], cv, offTa);
        offCa = fmaf(caR[e * 64 + d], cv, offCa);
    }

    // ---- A part ----
    float aT = mT + offTa, aC = mC + offCa;
    float M  = fmaxf(aT, aC);
    float eT = expf(aT - M), eC = expf(aC - M);
    float denom = eT * seT + eC * seC;
    float Apart = w_mix[d] * (eT * swT + eC * swC) / denom;

    // ---- B part = sum of slice partials (ascending order) ----
    float acc = 0.0f;
#pragma unroll 4
    for (int s = 0; s < nsl; s++) acc += accW[((s * 2 + b) * 512 + k) * 64 + d];
    float mval = Apart + acc;

    mS[kl][d] = mval;
    sS[kl][d] = snapB[(t + kk) * 64 + d];
    __syncthreads();

    // ---- u, o, update (verified) ----
    const float* uL = wT + 8 * 4096;
    const float* uR = wT + 9 * 4096;
    const float* oL = wT + 10 * 4096;
    const float* oR = wT + 11 * 4096;
    float zU = b_u[d], zO = b_o[d];
#pragma unroll 8
    for (int e = 0; e < 64; e++) {
        float mv = mS[kl][e], sv = sS[kl][e];
        zU = fmaf(mv, uL[e * 64 + d], zU);
        zU = fmaf(sv, uR[e * 64 + d], zU);
        zO = fmaf(mv, oL[e * 64 + d], zO);
        zO = fmaf(sv, oR[e * 64 + d], zO);
    }
    float u  = 1.0f / (1.0f + expf(-zU));
    float o  = fmaxf(zO, 0.0f);
    float mm = mS[kl][d];
    float sv = sS[kl][d];
    float upd = u * o + (1.0f - u) * mm - sv;

    float* Hb = H + b * NNODES * D;
    if (valid) {
        Hb[(i + k) * D + d] += upd;
        if (storeUpd) updWS[b * 2048 + k * 64 + d] = upd;
    }
    if (reapply && blockIdx.x == 0) {
#pragma unroll
        for (int r = 0; r < 8; r++) {
            int idx = threadIdx.x + 256 * r;  // 2048 = 32 nodes * 64
            Hb[(prev_i + (idx >> 6)) * D + (idx & 63)] += updWS[b * 2048 + idx];
        }
    }
}

// ---------------- fallback: r9 mono k_gate, byte-identical ----------------
__global__ void k_gate(float* __restrict__ H,
                       const float* __restrict__ wT,
                       const float* __restrict__ snap,
                       const float* __restrict__ Pb,
                       const float* __restrict__ stFin,
                       const float* __restrict__ b_ta, const float* __restrict__ b_ca,
                       const float* __restrict__ b_tb, const float* __restrict__ b_cb,
                       const float* __restrict__ w_mix,
                       const float* __restrict__ b_u, const float* __restrict__ b_o,
                       float* __restrict__ updWS,
                       int off, int t, int c, int storeUpd, int reapply, int prev_i)
{
    __shared__ float PS[CN][D];
    __shared__ float SS[CN][D];
    __shared__ float mS[4][64];
    __shared__ float sS[4][64];
    int b  = blockIdx.y;
    int kl = threadIdx.x >> 6;
    int d  = threadIdx.x & 63;
    int k  = blockIdx.x * 4 + kl;
    int valid = (k < c) ? 1 : 0;
    int i = off + t;
    const float* snapB = snap + b * SNAPN * D;
    const float* PbB   = Pb   + b * SNAPN * D;

    const float* fB = stFin + b * 384;
    float mT = fB[d],       seT = fB[64 + d],  swT = fB[128 + d];
    float mC = fB[192 + d], seC = fB[256 + d], swC = fB[320 + d];

    float offTa = b_ta[d], offCa = b_ca[d], offTb = b_tb[d], offCb = b_cb[d];
    const float* taR = wT + 1 * 4096;
    const float* caR = wT + 3 * 4096;
    const float* tbR = wT + 5 * 4096;
    const float* cbR = wT + 7 * 4096;
    int kk = valid ? k : 0;
    const float* cptr = snapB + (t + kk) * 64;
#pragma unroll 8
    for (int e = 0; e < 64; e++) {
        float cv = cptr[e];
        offTa = fmaf(taR[e * 64 + d], cv, offTa);
        offCa = fmaf(caR[e * 64 + d], cv, offCa);
        offTb = fmaf(tbR[e * 64 + d], cv, offTb);
        offCb = fmaf(cbR[e * 64 + d], cv, offCb);
    }

    float aT = mT + offTa, aC = mC + offCa;
    float M  = fmaxf(aT, aC);
    float eT = expf(aT - M), eC = expf(aC - M);
    float denom = eT * seT + eC * seC;
    float Apart = w_mix[d] * (eT * swT + eC * swC) / denom;

    float acc = 0.0f;
    int NTOT = t + c;
    for (int n0 = 0; n0 < NTOT; n0 += CN) {
        int cnt = NTOT - n0; if (cnt > CN) cnt = CN;
        __syncthreads();
        int tot4 = cnt * (D / 4);
        const float4* gp = (const float4*)(PbB   + n0 * D);
        const float4* gs = (const float4*)(snapB + n0 * D);
        float4* lp = (float4*)&PS[0][0];
        float4* ls = (float4*)&SS[0][0];
        for (int idx4 = threadIdx.x; idx4 < tot4; idx4 += 256) {
            lp[idx4] = gp[idx4];
            ls[idx4] = gs[idx4];
        }
        __syncthreads();
#pragma unroll 8
        for (int n = 0; n < cnt; n++) {
            int gn = n0 + n;
            float p = PS[n][d] + ((gn < t) ? offTb : offCb);
            float f = p / (1.0f + fabsf(p));
            acc = fmaf(f, SS[n][d], acc);
        }
    }
    float mval = Apart + acc;

    mS[kl][d] = mval;
    sS[kl][d] = snapB[(t + kk) * 64 + d];
    __syncthreads();

    const float* uL = wT + 8 * 4096;
    const float* uR = wT + 9 * 4096;
    const float* oL = wT + 10 * 4096;
    const float* oR = wT + 11 * 4096;
    float zU = b_u[d], zO = b_o[d];
#pragma unroll 8
    for (int e = 0; e < 64; e++) {
        float mv = mS[kl][e], sv = sS[kl][e];
        zU = fmaf(mv, uL[e * 64 + d], zU);
        zU = fmaf(sv, uR[e * 64 + d], zU);
        zO = fmaf(mv, oL[e * 64 + d], zO);
        zO = fmaf(sv, oR[e * 64 + d], zO);
    }
    float u  = 1.0f / (1.0f + expf(-zU));
    float o  = fmaxf(zO, 0.0f);
    float mm = mS[kl][d];
    float sv = sS[kl][d];
    float upd = u * o + (1.0f - u) * mm - sv;

    float* Hb = H + b * NNODES * D;
    if (valid) {
        Hb[(i + k) * D + d] += upd;
        if (storeUpd) updWS[b * 2048 + k * 64 + d] = upd;
    }
    if (reapply && blockIdx.x == 0) {
#pragma unroll
        for (int r = 0; r < 8; r++) {
            int idx = threadIdx.x + 256 * r;
            Hb[(prev_i + (idx >> 6)) * D + (idx & 63)] += updWS[b * 2048 + idx];
        }
    }
}

extern "C" void kernel_launch(void* const* d_in, const int* in_sizes, int n_in,
                              void* d_out, int out_size, void* d_ws, size_t ws_size,
                              hipStream_t stream) {
    const float* x    = (const float*)d_in[0];
    const float* w_ta = (const float*)d_in[2];
    const float* b_ta = (const float*)d_in[3];
    const float* w_ca = (const float*)d_in[4];
    const float* b_ca = (const float*)d_in[5];
    const float* w_tb = (const float*)d_in[6];
    const float* b_tb = (const float*)d_in[7];
    const float* w_cb = (const float*)d_in[8];
    const float* b_cb = (const float*)d_in[9];
    const float* w_mix= (const float*)d_in[10];
    const float* w_u  = (const float*)d_in[11];
    const float* b_u  = (const float*)d_in[12];
    const float* w_o  = (const float*)d_in[13];
    const float* b_o  = (const float*)d_in[14];

    float* H  = (float*)d_out;           // evolving state, [2][545][64]
    float* ws = (float*)d_ws;
    float* wT    = ws;                   // 12*4096 = 49152
    float* snap  = wT + 49152;           // 69632
    float* Pb    = snap + 69632;         // 69632
    float* stT   = Pb + 69632;           // 49152
    float* stC   = stT + 49152;          // 49152
    float* upd   = stC + 49152;          // 4096
    float* stFin = upd + 4096;           // 768
    float* accW  = stFin + 768;          // NSLMAX*2*512*64 = 1048576
    float* stMid = accW + 1048576;       // 2*2*NMS*3*64 = 6144

    const size_t NEEDED = (size_t)(49152 + 69632 + 69632 + 49152 + 49152 + 4096 + 768
                                   + (size_t)NSLMAX * 2 * 512 * 64 + 2 * 2 * NMS * 192) * 4;
    int useSplit = (ws_size >= NEEDED) ? 1 : 0;

    {
        int total = 2 * NNODES * D + 12 * 4096;
        k_init<<<dim3((total + 255) / 256), 256, 0, stream>>>(
            x, w_ta, w_ca, w_tb, w_cb, w_u, w_o, H, wT);
    }

    struct St { int off, t, c, store, reapply, prev_i; };
    const St steps[4] = {
        {0,   1,  32, 1, 0, 0},
        {1,  32, 512, 0, 1, 1},
        {0, 512,  32, 1, 0, 0},
        {512, 32,  1, 0, 1, 512},
    };
    for (int p = 0; p < 2; p++) {
        for (int s = 0; s < 4; s++) {
            St st = steps[s];
            int tilesT = (st.t + 3) / 4, tilesC = (st.c + 3) / 4;
            k_stage<<<dim3(tilesT + tilesC, 2), 256, 0, stream>>>(
                H, wT, snap, Pb, stT, stC, st.off, st.t, st.c);
            int kblk = (st.c + 3) / 4;
            int tiny = (st.t + st.c) <= 64;
            if (!useSplit) {
                k_merge<<<dim3(2, 2), 64, 0, stream>>>(
                    stT, stC, stFin, st.t, st.c);
                k_gate<<<dim3(kblk, 2), 256, 0, stream>>>(
                    H, wT, snap, Pb, stFin,
                    b_ta, b_ca, b_tb, b_cb, w_mix, b_u, b_o, upd,
                    st.off, st.t, st.c, st.store, st.reapply, st.prev_i);
            } else if (tiny) {
                k_gate4<<<dim3(kblk, 2), 256, 0, stream>>>(
                    H, wT, snap, Pb, stT, stC,
                    b_ta, b_ca, b_tb, b_cb, w_mix, b_u, b_o, upd,
                    st.off, st.t, st.c, st.store, st.reapply, st.prev_i);
            } else {
                const int nsl = 8;
                k_part<<<dim3(kblk + 4, nsl, 2), 256, 0, stream>>>(
                    wT, snap, Pb, b_tb, b_cb, stT, stC, stMid, accW,
                    st.off, st.t, st.c, nsl);
                k_fin<<<dim3(kblk, 2), 256, 0, stream>>>(
                    H, wT, snap, stMid, b_ta, b_ca, w_mix, b_u, b_o, accW, upd,
                    st.off, st.t, st.c, st.store, st.reapply, st.prev_i, nsl);
            }
        }
    }
}

// Round 16
// 208.780 us; speedup vs baseline: 1.0934x; 1.0818x over previous
//
#include <hip/hip_runtime.h>

#define D 64
#define NNODES 545
#define SNAPN 544   // max t+c
#define CN  64      // n-chunk rows staged in LDS (mono k_gate fallback)
#define CNP 32      // n-chunk rows staged in LDS (k_part)
#define NSL 4       // n-slices (k_part grid.y)
#define NMS 8       // merge slices

// ---------------- init: copy x -> H (d_out), transpose weights into ws ----------------
// wT layout (12 mats of 64x64, [e][d]): 0 taL,1 taR,2 caL,3 caR,4 tbL,5 tbR,6 cbL,7 cbR,8 uL,9 uR,10 oL,11 oR
__global__ void k_init(const float* __restrict__ x,
                       const float* __restrict__ w_ta, const float* __restrict__ w_ca,
                       const float* __restrict__ w_tb, const float* __restrict__ w_cb,
                       const float* __restrict__ w_u,  const float* __restrict__ w_o,
                       float* __restrict__ H, float* __restrict__ wT)
{
    int idx = blockIdx.x * 256 + threadIdx.x;
    const int NH = 2 * NNODES * D;  // 69760
    if (idx < NH) { H[idx] = x[idx]; return; }
    int j = idx - NH;
    if (j >= 12 * 4096) return;
    int mat = j >> 12;
    int r   = j & 4095;
    int e   = r >> 6;
    int dd  = r & 63;
    const float* src;
    switch (mat >> 1) {
        case 0: src = w_ta; break;
        case 1: src = w_ca; break;
        case 2: src = w_tb; break;
        case 3: src = w_cb; break;
        case 4: src = w_u;  break;
        default: src = w_o; break;
    }
    int half = mat & 1;
    wT[j] = src[dd * 128 + half * 64 + e];
}

// ---------------- kernel A: staging (verified body) + Q-offset hoist ------------------
// For region-C tiles, Hs[ln][:] IS the C row for k = n0+ln, so the four per-(k,d)
// gate offsets are computed here once (same fmaf order as part/fin originals ->
// bitwise-identical values) and staged to Qoff[mat][b][k][d].
__global__ void k_stage(const float* __restrict__ H,
                        const float* __restrict__ wT,
                        float* __restrict__ snap,   // [2][544][64]
                        float* __restrict__ Pb,     // [2][544][64]
                        float* __restrict__ stT,    // [2][3][128][64]
                        float* __restrict__ stC,    // [2][3][128][64]
                        const float* __restrict__ b_ta, const float* __restrict__ b_ca,
                        const float* __restrict__ b_tb, const float* __restrict__ b_cb,
                        float* __restrict__ Qoff, int qon,
                        int off, int t, int c)
{
    __shared__ float Hs[4][64];
    __shared__ float PaS[4][64];
    int b = blockIdx.y;
    int tilesT = (t + 3) >> 2;
    int tile = blockIdx.x;
    int ln = threadIdx.x >> 6;
    int d  = threadIdx.x & 63;
    int regionC = (tile >= tilesT) ? 1 : 0;
    int tl = regionC ? (tile - tilesT) : tile;
    int n0 = tl * 4;
    int cnt = regionC ? c : t;
    int nodeBase = off + (regionC ? t : 0);
    int valid = (n0 + ln) < cnt;
    const float* Hb = H + b * NNODES * D;

    Hs[ln][d] = valid ? Hb[(nodeBase + n0 + ln) * D + d] : 0.0f;
    __syncthreads();

    const float* wA = wT + (regionC ? 2 * 4096 : 0);        // caL : taL
    const float* wB = wT + (regionC ? 6 * 4096 : 4 * 4096); // cbL : tbL
    float acc_a = 0.0f, acc_b = 0.0f;
#pragma unroll 8
    for (int e = 0; e < 64; e++) {
        float h = Hs[ln][e];
        acc_a = fmaf(wA[e * 64 + d], h, acc_a);
        acc_b = fmaf(wB[e * 64 + d], h, acc_b);
    }
    int gn = (regionC ? t : 0) + n0 + ln;
    float* snapB = snap + b * SNAPN * D;
    float* PbB   = Pb   + b * SNAPN * D;
    if (valid) {
        PbB[gn * D + d]   = acc_b;
        snapB[gn * D + d] = Hs[ln][d];
    }

    // ---- Q-offset hoist (bitwise-identical fmaf sequence to part/fin originals) ----
    if (qon && regionC) {
        const float* taR = wT + 1 * 4096;
        const float* caR = wT + 3 * 4096;
        const float* tbR = wT + 5 * 4096;
        const float* cbR = wT + 7 * 4096;
        float oTa = b_ta[d], oCa = b_ca[d], oTb = b_tb[d], oCb = b_cb[d];
#pragma unroll 8
        for (int e = 0; e < 64; e++) {
            float cv = Hs[ln][e];
            oTa = fmaf(taR[e * 64 + d], cv, oTa);
            oCa = fmaf(caR[e * 64 + d], cv, oCa);
            oTb = fmaf(tbR[e * 64 + d], cv, oTb);
            oCb = fmaf(cbR[e * 64 + d], cv, oCb);
        }
        if (valid) {
            int k = n0 + ln;
            Qoff[0 * 65536 + b * 32768 + k * 64 + d] = oTa;
            Qoff[1 * 65536 + b * 32768 + k * 64 + d] = oCa;
            Qoff[2 * 65536 + b * 32768 + k * 64 + d] = oTb;
            Qoff[3 * 65536 + b * 32768 + k * 64 + d] = oCb;
        }
    }

    PaS[ln][d] = valid ? acc_a : -3.0e38f;
    __syncthreads();

    if (threadIdx.x < 64) {
        int dd = threadIdx.x;
        float mx = -3.0e38f;
#pragma unroll
        for (int l = 0; l < 4; l++) mx = fmaxf(mx, PaS[l][dd]);
        int lim = cnt - n0; if (lim > 4) lim = 4;
        float se = 0.0f, sw = 0.0f;
        for (int l = 0; l < lim; l++) {
            float ev = expf(PaS[l][dd] - mx);
            se += ev;
            sw += ev * Hs[l][dd];
        }
        float* st = (regionC ? stC : stT) + b * 3 * 128 * 64;
        st[0 * 8192 + tl * 64 + dd] = mx;
        st[1 * 8192 + tl * 64 + dd] = se;
        st[2 * 8192 + tl * 64 + dd] = sw;
    }
}

// ---------------- k_merge: single-level merge (fallback path only; verified r7/9) -----
__global__ void k_merge(const float* __restrict__ stT,
                        const float* __restrict__ stC,
                        float* __restrict__ stFin,
                        int t, int c)
{
    int r = blockIdx.x;
    int b = blockIdx.y;
    int d = threadIdx.x;
    const float* st = (r ? stC : stT) + b * 3 * 8192;
    int cnt = r ? c : t;
    int ntl = (cnt + 3) >> 2;
    float m = -3.0e38f, se = 0.0f, sw = 0.0f;
    for (int tl = 0; tl < ntl; tl++) {
        float m1 = st[tl * 64 + d];
        float s1 = st[8192 + tl * 64 + d];
        float w1 = st[2 * 8192 + tl * 64 + d];
        float nm = fmaxf(m, m1);
        float f0 = expf(m - nm), f1 = expf(m1 - nm);
        se = se * f0 + s1 * f1;
        sw = sw * f0 + w1 * f1;
        m  = nm;
    }
    float* o = stFin + (b * 2 + r) * 192;
    o[d] = m; o[64 + d] = se; o[128 + d] = sw;
}

// ---------------- k_part: r12-verified LDS-staged B-partials + mergeA riders ----------
// grid: (kblk + 4, NSL, 2). Blocks with blockIdx.x >= kblk run the mergeA body.
__global__ void k_part(const float* __restrict__ wT,
                       const float* __restrict__ snap,
                       const float* __restrict__ Pb,
                       const float* __restrict__ Qoff,
                       const float* __restrict__ stT, const float* __restrict__ stC,
                       float* __restrict__ stMid,  // [(b*2+r)*NMS+s][3][64]
                       float* __restrict__ accW,   // [NSL][2][512][64]
                       int off, int t, int c)
{
    __shared__ float PS[CNP][D];
    __shared__ float SS[CNP][D];
    int kblk = gridDim.x - 4;
    int b  = blockIdx.z;

    if (blockIdx.x >= kblk) {
        // ---- mergeA rider (verbatim r11/12) ----
        if (threadIdx.x < 64) {
            int e = blockIdx.x - kblk;        // 0..3
            int r = e >> 1;                   // region
            int s = (e & 1) * 4 + blockIdx.y; // slice 0..7
            int d = threadIdx.x;
            const float* st = (r ? stC : stT) + b * 3 * 8192;
            int cnt = r ? c : t;
            int ntl = (cnt + 3) >> 2;
            int tl0 = s * 16, tl1 = tl0 + 16; if (tl1 > ntl) tl1 = ntl;
            float m = -3.0e38f, se = 0.0f, sw = 0.0f;
            for (int tl = tl0; tl < tl1; tl++) {
                float m1 = st[tl * 64 + d];
                float s1 = st[8192 + tl * 64 + d];
                float w1 = st[2 * 8192 + tl * 64 + d];
                float nm = fmaxf(m, m1);
                float f0 = expf(m - nm), f1 = expf(m1 - nm);
                se = se * f0 + s1 * f1;
                sw = sw * f0 + w1 * f1;
                m  = nm;
            }
            float* o = stMid + ((b * 2 + r) * NMS + s) * 192;
            o[d] = m; o[64 + d] = se; o[128 + d] = sw;
        }
        return;
    }

    int s  = blockIdx.y;
    int kl = threadIdx.x >> 6;
    int d  = threadIdx.x & 63;
    int k  = blockIdx.x * 4 + kl;
    int valid = (k < c) ? 1 : 0;
    int kk = valid ? k : 0;
    const float* snapB = snap + b * SNAPN * D;
    const float* PbB   = Pb   + b * SNAPN * D;

    // ---- b-gate offsets: precomputed by k_stage (bitwise-identical values) ----
    float offTb = Qoff[2 * 65536 + b * 32768 + kk * 64 + d];
    float offCb = Qoff[3 * 65536 + b * 32768 + kk * 64 + d];

    // ---- B-part over this slice's chunk range (verbatim r12) ----
    int NTOT = t + c;
    int nch = (NTOT + CNP - 1) / CNP;
    int cps = (nch + NSL - 1) / NSL;
    int ch0 = s * cps, ch1 = ch0 + cps; if (ch1 > nch) ch1 = nch;
    float acc = 0.0f;
    for (int ch = ch0; ch < ch1; ch++) {
        int n0 = ch * CNP;
        int cnt = NTOT - n0; if (cnt > CNP) cnt = CNP;
        __syncthreads();   // protect previous chunk's reads before overwrite
        int tot4 = cnt * (D / 4);
        const float4* gp = (const float4*)(PbB   + n0 * D);
        const float4* gs = (const float4*)(snapB + n0 * D);
        float4* lp = (float4*)&PS[0][0];
        float4* ls = (float4*)&SS[0][0];
        for (int idx4 = threadIdx.x; idx4 < tot4; idx4 += 256) {
            lp[idx4] = gp[idx4];
            ls[idx4] = gs[idx4];
        }
        __syncthreads();
#pragma unroll 8
        for (int n = 0; n < cnt; n++) {
            int gn = n0 + n;
            float p = PS[n][d] + ((gn < t) ? offTb : offCb);
            float f = p / (1.0f + fabsf(p));
            acc = fmaf(f, SS[n][d], acc);
        }
    }
    accW[((s * 2 + b) * 512 + k) * 64 + d] = acc;
}

// ---------------- k_fin: combine + epilogue (r12 body; offsets from Qoff) -------------
__global__ void k_fin(float* __restrict__ H,
                      const float* __restrict__ wT,
                      const float* __restrict__ snap,
                      const float* __restrict__ stMid,
                      const float* __restrict__ Qoff,
                      const float* __restrict__ w_mix,
                      const float* __restrict__ b_u, const float* __restrict__ b_o,
                      const float* __restrict__ accW,
                      float* __restrict__ updWS,
                      int off, int t, int c, int storeUpd, int reapply, int prev_i)
{
    __shared__ float mS[4][64];
    __shared__ float sS[4][64];
    int b  = blockIdx.y;
    int kl = threadIdx.x >> 6;
    int d  = threadIdx.x & 63;
    int k  = blockIdx.x * 4 + kl;
    int valid = (k < c) ? 1 : 0;
    int i = off + t;
    int kk = valid ? k : 0;
    const float* snapB = snap + b * SNAPN * D;

    // ---- mergeB inlined (verbatim r12) ----
    float mT = -3.0e38f, seT = 0.0f, swT = 0.0f;
    {
        const float* base = stMid + (b * 2 + 0) * NMS * 192;
#pragma unroll
        for (int s = 0; s < NMS; s++) {
            const float* p = base + s * 192;
            float m1 = p[d], s1 = p[64 + d], w1 = p[128 + d];
            float nm = fmaxf(mT, m1);
            float f0 = expf(mT - nm), f1 = expf(m1 - nm);
            seT = seT * f0 + s1 * f1;
            swT = swT * f0 + w1 * f1;
            mT = nm;
        }
    }
    float mC = -3.0e38f, seC = 0.0f, swC = 0.0f;
    {
        const float* base = stMid + (b * 2 + 1) * NMS * 192;
#pragma unroll
        for (int s = 0; s < NMS; s++) {
            const float* p = base + s * 192;
            float m1 = p[d], s1 = p[64 + d], w1 = p[128 + d];
            float nm = fmaxf(mC, m1);
            float f0 = expf(mC - nm), f1 = expf(m1 - nm);
            seC = seC * f0 + s1 * f1;
            swC = swC * f0 + w1 * f1;
            mC = nm;
        }
    }

    // ---- a-gate offsets: precomputed by k_stage (bitwise-identical values) ----
    float offTa = Qoff[0 * 65536 + b * 32768 + kk * 64 + d];
    float offCa = Qoff[1 * 65536 + b * 32768 + kk * 64 + d];

    // ---- A part ----
    float aT = mT + offTa, aC = mC + offCa;
    float M  = fmaxf(aT, aC);
    float eT = expf(aT - M), eC = expf(aC - M);
    float denom = eT * seT + eC * seC;
    float Apart = w_mix[d] * (eT * swT + eC * swC) / denom;

    // ---- B part = sum of slice partials (ascending order) ----
    float acc = 0.0f;
#pragma unroll
    for (int s = 0; s < NSL; s++) acc += accW[((s * 2 + b) * 512 + k) * 64 + d];
    float mval = Apart + acc;

    mS[kl][d] = mval;
    sS[kl][d] = snapB[(t + kk) * 64 + d];
    __syncthreads();

    // ---- u, o, update (verbatim r12) ----
    const float* uL = wT + 8 * 4096;
    const float* uR = wT + 9 * 4096;
    const float* oL = wT + 10 * 4096;
    const float* oR = wT + 11 * 4096;
    float zU = b_u[d], zO = b_o[d];
#pragma unroll 8
    for (int e = 0; e < 64; e++) {
        float mv = mS[kl][e], sv = sS[kl][e];
        zU = fmaf(mv, uL[e * 64 + d], zU);
        zU = fmaf(sv, uR[e * 64 + d], zU);
        zO = fmaf(mv, oL[e * 64 + d], zO);
        zO = fmaf(sv, oR[e * 64 + d], zO);
    }
    float u  = 1.0f / (1.0f + expf(-zU));
    float o  = fmaxf(zO, 0.0f);
    float mm = mS[kl][d];
    float sv = sS[kl][d];
    float upd = u * o + (1.0f - u) * mm - sv;

    float* Hb = H + b * NNODES * D;
    if (valid) {
        Hb[(i + k) * D + d] += upd;
        if (storeUpd) updWS[b * 2048 + k * 64 + d] = upd;
    }
    if (reapply && blockIdx.x == 0) {
#pragma unroll
        for (int r = 0; r < 8; r++) {
            int idx = threadIdx.x + 256 * r;  // 2048 = 32 nodes * 64
            Hb[(prev_i + (idx >> 6)) * D + (idx & 63)] += updWS[b * 2048 + idx];
        }
    }
}

// ---------------- fallback: r9 mono k_gate, byte-identical ----------------
__global__ void k_gate(float* __restrict__ H,
                       const float* __restrict__ wT,
                       const float* __restrict__ snap,
                       const float* __restrict__ Pb,
                       const float* __restrict__ stFin,
                       const float* __restrict__ b_ta, const float* __restrict__ b_ca,
                       const float* __restrict__ b_tb, const float* __restrict__ b_cb,
                       const float* __restrict__ w_mix,
                       const float* __restrict__ b_u, const float* __restrict__ b_o,
                       float* __restrict__ updWS,
                       int off, int t, int c, int storeUpd, int reapply, int prev_i)
{
    __shared__ float PS[CN][D];
    __shared__ float SS[CN][D];
    __shared__ float mS[4][64];
    __shared__ float sS[4][64];
    int b  = blockIdx.y;
    int kl = threadIdx.x >> 6;
    int d  = threadIdx.x & 63;
    int k  = blockIdx.x * 4 + kl;
    int valid = (k < c) ? 1 : 0;
    int i = off + t;
    const float* snapB = snap + b * SNAPN * D;
    const float* PbB   = Pb   + b * SNAPN * D;

    const float* fB = stFin + b * 384;
    float mT = fB[d],       seT = fB[64 + d],  swT = fB[128 + d];
    float mC = fB[192 + d], seC = fB[256 + d], swC = fB[320 + d];

    float offTa = b_ta[d], offCa = b_ca[d], offTb = b_tb[d], offCb = b_cb[d];
    const float* taR = wT + 1 * 4096;
    const float* caR = wT + 3 * 4096;
    const float* tbR = wT + 5 * 4096;
    const float* cbR = wT + 7 * 4096;
    int kk = valid ? k : 0;
    const float* cptr = snapB + (t + kk) * 64;
#pragma unroll 8
    for (int e = 0; e < 64; e++) {
        float cv = cptr[e];
        offTa = fmaf(taR[e * 64 + d], cv, offTa);
        offCa = fmaf(caR[e * 64 + d], cv, offCa);
        offTb = fmaf(tbR[e * 64 + d], cv, offTb);
        offCb = fmaf(cbR[e * 64 + d], cv, offCb);
    }

    float aT = mT + offTa, aC = mC + offCa;
    float M  = fmaxf(aT, aC);
    float eT = expf(aT - M), eC = expf(aC - M);
    float denom = eT * seT + eC * seC;
    float Apart = w_mix[d] * (eT * swT + eC * swC) / denom;

    float acc = 0.0f;
    int NTOT = t + c;
    for (int n0 = 0; n0 < NTOT; n0 += CN) {
        int cnt = NTOT - n0; if (cnt > CN) cnt = CN;
        __syncthreads();
        int tot4 = cnt * (D / 4);
        const float4* gp = (const float4*)(PbB   + n0 * D);
        const float4* gs = (const float4*)(snapB + n0 * D);
        float4* lp = (float4*)&PS[0][0];
        float4* ls = (float4*)&SS[0][0];
        for (int idx4 = threadIdx.x; idx4 < tot4; idx4 += 256) {
            lp[idx4] = gp[idx4];
            ls[idx4] = gs[idx4];
        }
        __syncthreads();
#pragma unroll 8
        for (int n = 0; n < cnt; n++) {
            int gn = n0 + n;
            float p = PS[n][d] + ((gn < t) ? offTb : offCb);
            float f = p / (1.0f + fabsf(p));
            acc = fmaf(f, SS[n][d], acc);
        }
    }
    float mval = Apart + acc;

    mS[kl][d] = mval;
    sS[kl][d] = snapB[(t + kk) * 64 + d];
    __syncthreads();

    const float* uL = wT + 8 * 4096;
    const float* uR = wT + 9 * 4096;
    const float* oL = wT + 10 * 4096;
    const float* oR = wT + 11 * 4096;
    float zU = b_u[d], zO = b_o[d];
#pragma unroll 8
    for (int e = 0; e < 64; e++) {
        float mv = mS[kl][e], sv = sS[kl][e];
        zU = fmaf(mv, uL[e * 64 + d], zU);
        zU = fmaf(sv, uR[e * 64 + d], zU);
        zO = fmaf(mv, oL[e * 64 + d], zO);
        zO = fmaf(sv, oR[e * 64 + d], zO);
    }
    float u  = 1.0f / (1.0f + expf(-zU));
    float o  = fmaxf(zO, 0.0f);
    float mm = mS[kl][d];
    float sv = sS[kl][d];
    float upd = u * o + (1.0f - u) * mm - sv;

    float* Hb = H + b * NNODES * D;
    if (valid) {
        Hb[(i + k) * D + d] += upd;
        if (storeUpd) updWS[b * 2048 + k * 64 + d] = upd;
    }
    if (reapply && blockIdx.x == 0) {
#pragma unroll
        for (int r = 0; r < 8; r++) {
            int idx = threadIdx.x + 256 * r;
            Hb[(prev_i + (idx >> 6)) * D + (idx & 63)] += updWS[b * 2048 + idx];
        }
    }
}

extern "C" void kernel_launch(void* const* d_in, const int* in_sizes, int n_in,
                              void* d_out, int out_size, void* d_ws, size_t ws_size,
                              hipStream_t stream) {
    const float* x    = (const float*)d_in[0];
    const float* w_ta = (const float*)d_in[2];
    const float* b_ta = (const float*)d_in[3];
    const float* w_ca = (const float*)d_in[4];
    const float* b_ca = (const float*)d_in[5];
    const float* w_tb = (const float*)d_in[6];
    const float* b_tb = (const float*)d_in[7];
    const float* w_cb = (const float*)d_in[8];
    const float* b_cb = (const float*)d_in[9];
    const float* w_mix= (const float*)d_in[10];
    const float* w_u  = (const float*)d_in[11];
    const float* b_u  = (const float*)d_in[12];
    const float* w_o  = (const float*)d_in[13];
    const float* b_o  = (const float*)d_in[14];

    float* H  = (float*)d_out;           // evolving state, [2][545][64]
    float* ws = (float*)d_ws;
    float* wT    = ws;                   // 12*4096 = 49152
    float* snap  = wT + 49152;           // 69632
    float* Pb    = snap + 69632;         // 69632
    float* stT   = Pb + 69632;           // 49152
    float* stC   = stT + 49152;          // 49152
    float* upd   = stC + 49152;          // 4096
    float* stFin = upd + 4096;           // 768
    float* accW  = stFin + 768;          // NSL*2*512*64 = 262144
    float* stMid = accW + 262144;        // 2*2*NMS*3*64 = 6144
    float* Qoff  = stMid + 6144;         // 4*2*512*64 = 262144  (total ~3.29MB)

    const size_t NEEDED = (size_t)(49152 + 69632 + 69632 + 49152 + 49152 + 4096 + 768
                                   + 262144 + 6144 + 262144) * 4;
    int useSplit = (ws_size >= NEEDED) ? 1 : 0;

    {
        int total = 2 * NNODES * D + 12 * 4096;
        k_init<<<dim3((total + 255) / 256), 256, 0, stream>>>(
            x, w_ta, w_ca, w_tb, w_cb, w_u, w_o, H, wT);
    }

    struct St { int off, t, c, store, reapply, prev_i; };
    const St steps[4] = {
        {0,   1,  32, 1, 0, 0},
        {1,  32, 512, 0, 1, 1},
        {0, 512,  32, 1, 0, 0},
        {512, 32,  1, 0, 1, 512},
    };
    for (int p = 0; p < 2; p++) {
        for (int s = 0; s < 4; s++) {
            St st = steps[s];
            int tilesT = (st.t + 3) / 4, tilesC = (st.c + 3) / 4;
            k_stage<<<dim3(tilesT + tilesC, 2), 256, 0, stream>>>(
                H, wT, snap, Pb, stT, stC,
                b_ta, b_ca, b_tb, b_cb, Qoff, useSplit,
                st.off, st.t, st.c);
            int kblk = (st.c + 3) / 4;
            if (useSplit) {
                k_part<<<dim3(kblk + 4, NSL, 2), 256, 0, stream>>>(
                    wT, snap, Pb, Qoff, stT, stC, stMid, accW,
                    st.off, st.t, st.c);
                k_fin<<<dim3(kblk, 2), 256, 0, stream>>>(
                    H, wT, snap, stMid, Qoff, w_mix, b_u, b_o, accW, upd,
                    st.off, st.t, st.c, st.store, st.reapply, st.prev_i);
            } else {
                k_merge<<<dim3(2, 2), 64, 0, stream>>>(
                    stT, stC, stFin, st.t, st.c);
                k_gate<<<dim3(kblk, 2), 256, 0, stream>>>(
                    H, wT, snap, Pb, stFin,
                    b_ta, b_ca, b_tb, b_cb, w_mix, b_u, b_o, upd,
                    st.off, st.t, st.c, st.store, st.reapply, st.prev_i);
            }
        }
    }
}